// Round 2
// baseline (2941.754 us; speedup 1.0000x reference)
//
#include <hip/hip_runtime.h>

typedef unsigned short u16;
typedef unsigned int   u32;
typedef __attribute__((ext_vector_type(8))) short bf16x8;
typedef __attribute__((ext_vector_type(4))) float f32x4;
typedef __attribute__((ext_vector_type(4))) u32 u32x4;

#define NBLK 64
#define NTHR 512
#define T_SEQ 300

// workspace layout (bytes) — all offsets 16B-aligned
#define OFF_WP   0u            // packed weights bf16: 512 tiles * 21 ksteps * 64 lanes * 16B = 11,010,048
#define OFF_BP   11010048u     // packed bias f32[8192] = 32,768
#define OFF_XB   11042816u     // x bf16 K-slot layout: 300*128*192*2 = 14,745,600
#define OFF_H    25788416u     // h arena bf16: 301 * 128*512 * 2B = 39,452,672
#define OFF_BAR  65241088u     // 2 ints (arrive counter, generation)

__device__ __forceinline__ float bf2f(u16 u){ union { u32 u; float f; } v; v.u = ((u32)u) << 16; return v.f; }
__device__ __forceinline__ u16 f2bf(float f){
  union { float f; u32 u; } v; v.f = f;
  u32 r = v.u + 0x7fffu + ((v.u >> 16) & 1u);
  return (u16)(r >> 16);
}
__device__ __forceinline__ float sigf(float x){ return 1.f / (1.f + __expf(-x)); }
__device__ __forceinline__ float tanh_f(float x){ return 1.f - 2.f / (1.f + __expf(2.f * x)); }

// ---------------------------------------------------------------------------
// prep: pack fp32 weights into bf16 MFMA B-fragment order, pack biases (f32),
// zero h[0], reset barrier.
// K-space per output column (672 = 21*32): [0,512) = hidden; [512,672) =
// 5 parts * 32 slots. Slot (p, cc, ii): d = cc*8+ii for cc<3; for cc==3,
// ii<2 -> weight ZERO (data duplicates x[22],x[23]), ii>=2 -> d = 22+ii.
// Gate tiles tt=p*3+g use only part p's slots; o-tile (tt=15) uses all (Wxo).
// ---------------------------------------------------------------------------
__global__ void prep(const float* __restrict__ Wx, const float* __restrict__ Wh,
                     const float* __restrict__ bg, const float* __restrict__ Wxo,
                     const float* __restrict__ Who, const float* __restrict__ bo,
                     u16* __restrict__ Wp, float* __restrict__ bpack,
                     u16* __restrict__ h0, int* __restrict__ bar)
{
  int w = blockIdx.x * 256 + threadIdx.x;

  if (w < 8192) {
    u32x4 z = {0u, 0u, 0u, 0u};
    ((u32x4*)h0)[w] = z;                       // zero h[0] (128*512 bf16)
    int tile = w >> 4, jc = w & 15;
    int jt = tile >> 4, tt = tile & 15, j = (jt << 4) + jc;
    float bv;
    if (tt < 15) { int p = tt / 3, g = tt - p * 3; bv = bg[p * 1536 + g * 512 + j]; }
    else bv = bo[j];
    bpack[w] = bv;
  }
  if (w == 0) { bar[0] = 0; bar[1] = 0; }

  int lane = w & 63, rem = w >> 6, kk = rem % 21, tile = rem / 21;
  if (tile < 512) {
    int jt = tile >> 4, tt = tile & 15;
    int j = (jt << 4) + (lane & 15);
    int k0 = kk * 32 + ((lane >> 4) << 3);
    union { u16 s[8]; u32x4 v; } o;
    #pragma unroll
    for (int i = 0; i < 8; ++i) {
      int k = k0 + i;
      float val = 0.f;
      if (tt < 15) {
        int p = tt / 3, g = tt - p * 3, col = g * 512 + j;
        if (k < 512) val = Wh[(p * 512 + k) * 1536 + col];
        else {
          int kx = k - 512, px = kx >> 5, cc = (kx >> 3) & 3, ii = kx & 7;
          int d = (cc < 3) ? cc * 8 + ii : ((ii < 2) ? -1 : 22 + ii);
          if (px == p && d >= 0) val = Wx[(p * 30 + d) * 1536 + col];
        }
      } else {
        if (k < 512) val = Who[k * 512 + j];
        else {
          int kx = k - 512, px = kx >> 5, cc = (kx >> 3) & 3, ii = kx & 7;
          int d = (cc < 3) ? cc * 8 + ii : ((ii < 2) ? -1 : 22 + ii);
          if (d >= 0) val = Wxo[(px * 30 + d) * 512 + j];
        }
      }
      o.s[i] = f2bf(val);
    }
    *(u32x4*)(Wp + (size_t)((tile * 21 + kk) * 64 + lane) * 8) = o.v;
  }
}

// ---------------------------------------------------------------------------
// prep_x: fp32 x [5][128][300][30] -> bf16 xb[t][bglob][slot] (slot 0..191,
// slots 160..191 zero pad). One thread = one 8-slot chunk (16B store).
// ---------------------------------------------------------------------------
__global__ void prep_x(const float* __restrict__ x, u16* __restrict__ xb)
{
  int w = blockIdx.x * 256 + threadIdx.x;          // 0 .. 921599
  int cx = w % 24, rem = w / 24;
  int bglob = rem % 128, t = rem / 128;
  union { u16 s[8]; u32x4 v; } o;
  int s0 = cx << 3;
  if (s0 >= 160) {
    u32x4 z = {0u, 0u, 0u, 0u}; o.v = z;
  } else {
    int p = s0 >> 5, cc = (s0 >> 3) & 3;
    const float* row = x + ((size_t)(p * 128 + bglob) * 300 + t) * 30;
    #pragma unroll
    for (int i = 0; i < 8; ++i) {
      int d = (cc < 3) ? cc * 8 + i : 22 + i;
      o.s[i] = f2bf(row[d]);
    }
  }
  *(u32x4*)(xb + (size_t)w * 8) = o.v;
}

// Fence-free grid barrier: monotonic arrive counter + generation, relaxed
// agent-scope atomics only (no buffer_inv/wbl2 -> weight L2 stays warm).
// Cross-block h data is safe via the rotating arena (addresses never re-read
// before their unique write) + __syncthreads draining vmcnt before arrival.
__device__ __forceinline__ void gbar(int* bar, int t)
{
  __syncthreads();
  if (threadIdx.x == 0) {
    if (__hip_atomic_fetch_add(&bar[0], 1, __ATOMIC_RELAXED, __HIP_MEMORY_SCOPE_AGENT)
        == t * NBLK + (NBLK - 1)) {
      __hip_atomic_store(&bar[1], t + 1, __ATOMIC_RELAXED, __HIP_MEMORY_SCOPE_AGENT);
    } else {
      while (__hip_atomic_load(&bar[1], __ATOMIC_RELAXED, __HIP_MEMORY_SCOPE_AGENT) <= t)
        __builtin_amdgcn_s_sleep(2);
    }
  }
  __syncthreads();
}

// ---------------------------------------------------------------------------
// Persistent part-LSTM. Block = (jt = 16-col slice of H) x (bh = batch half).
// Per step: stage h + x into swizzled LDS -> MFMA [64 x 672] . [672 x 256]
// -> gates (+bias) to LDS -> elementwise c/h update (c in fp32 registers) ->
// h_next bf16 via agent-scope stores into rotating arena -> grid barrier.
// ---------------------------------------------------------------------------
__global__ void __launch_bounds__(NTHR)
plstm(const u16* __restrict__ xb, const u16* __restrict__ Wp,
      const float* __restrict__ bpack, u16* hall, int* bar,
      const float* __restrict__ fcw, const float* __restrict__ fcb,
      float* __restrict__ out)
{
  __shared__ __align__(16) u16 Ash[64 * 512];   // 64 KB: h tiles; reused as f32 gates[64][256]
  __shared__ __align__(16) u16 Xsh[64 * 192];   // 24 KB: x K-slots (swizzled)
  float* gsh = (float*)Ash;

  const int tid  = threadIdx.x;
  const int lane = tid & 63;
  const int wv   = tid >> 6;          // 8 waves
  const int l15  = lane & 15;
  const int quad = lane >> 4;
  const int jt   = blockIdx.x >> 1;   // 0..31
  const int bh   = blockIdx.x & 1;    // batch half
  const int tt0  = wv << 1;           // this wave's two N-tiles

  const int erow = tid >> 3;          // elementwise: row 0..63
  const int jcp  = tid & 7;           // jc pair index

  float cr0[5], cr1[5];
  #pragma unroll
  for (int p = 0; p < 5; ++p) { cr0[p] = 0.f; cr1[p] = 0.f; }

  const u16* wpb0 = Wp + (size_t)((jt * 16 + tt0    ) * 21) * 512 + lane * 8;
  const u16* wpb1 = Wp + (size_t)((jt * 16 + tt0 + 1) * 21) * 512 + lane * 8;
  const float bias0 = bpack[((jt << 4) + tt0    ) * 16 + l15];
  const float bias1 = bpack[((jt << 4) + tt0 + 1) * 16 + l15];

  for (int t = 0; t < T_SEQ; ++t) {
    // ---- stage h[t] rows (own batch half) into LDS, chunk-XOR swizzle ----
    const u16* hprev = hall + (size_t)t * 65536;
    #pragma unroll
    for (int i = 0; i < 8; ++i) {
      int c = tid + (i << 9);
      int row = c >> 6, cc = c & 63;
      u32x4 v = *(const u32x4*)(hprev + (size_t)(((bh << 6) | row) << 9) + (cc << 3));
      *(u32x4*)(Ash + (row << 9) + ((cc ^ (row & 7)) << 3)) = v;
    }
    // ---- stage x[t] (own batch half) into LDS, chunk-XOR swizzle ----
    {
      const u16* xsrc = xb + (size_t)(t * 128 + (bh << 6)) * 192;
      #pragma unroll
      for (int i = 0; i < 3; ++i) {
        int c = tid + (i << 9);           // 0..1535
        int row = c / 24, cx = c - row * 24;
        u32x4 v = *(const u32x4*)(xsrc + (size_t)row * 192 + (cx << 3));
        *(u32x4*)(Xsh + row * 192 + ((cx ^ (row & 7)) << 3)) = v;
      }
    }
    __syncthreads();

    f32x4 acc0[4], acc1[4];
    #pragma unroll
    for (int m = 0; m < 4; ++m) {
      f32x4 z = {0.f, 0.f, 0.f, 0.f};
      acc0[m] = z; acc1[m] = z;
    }

    // ---- K-loop, hidden part (LDS A-frags) ----
    #pragma unroll 4
    for (int kk = 0; kk < 16; ++kk) {
      bf16x8 b0 = *(const bf16x8*)(wpb0 + kk * 512);
      bf16x8 b1 = *(const bf16x8*)(wpb1 + kk * 512);
      int c0 = (kk << 2) | quad;
      #pragma unroll
      for (int m = 0; m < 4; ++m) {
        int row = (m << 4) | l15;
        bf16x8 a = *(const bf16x8*)(Ash + (row << 9) + ((c0 ^ (row & 7)) << 3));
        acc0[m] = __builtin_amdgcn_mfma_f32_16x16x32_bf16(a, b0, acc0[m], 0, 0, 0);
        acc1[m] = __builtin_amdgcn_mfma_f32_16x16x32_bf16(a, b1, acc1[m], 0, 0, 0);
      }
    }
    // ---- K-loop, x part (LDS A-frags; zero-weight pad slots) ----
    #pragma unroll
    for (int kk = 0; kk < 5; ++kk) {
      bf16x8 b0 = *(const bf16x8*)(wpb0 + (16 + kk) * 512);
      bf16x8 b1 = *(const bf16x8*)(wpb1 + (16 + kk) * 512);
      int cf = (kk << 2) | quad;
      #pragma unroll
      for (int m = 0; m < 4; ++m) {
        int row = (m << 4) | l15;
        bf16x8 a = *(const bf16x8*)(Xsh + row * 192 + ((cf ^ (row & 7)) << 3));
        acc0[m] = __builtin_amdgcn_mfma_f32_16x16x32_bf16(a, b0, acc0[m], 0, 0, 0);
        acc1[m] = __builtin_amdgcn_mfma_f32_16x16x32_bf16(a, b1, acc1[m], 0, 0, 0);
      }
    }
    __syncthreads();   // all A reads done before gates overwrite LDS

    // ---- dump gates (+bias) to LDS, C/D layout: col=lane&15, row=quad*4+reg ----
    #pragma unroll
    for (int m = 0; m < 4; ++m) {
      #pragma unroll
      for (int r = 0; r < 4; ++r) {
        int row = (m << 4) + (quad << 2) + r;
        gsh[(row << 8) + (tt0 << 4) + l15]       = acc0[m][r] + bias0;
        gsh[(row << 8) + ((tt0 + 1) << 4) + l15] = acc1[m][r] + bias1;
      }
    }
    __syncthreads();

    // ---- elementwise: c update (registers), h_new -> agent-scope store ----
    {
      const float* gr = gsh + (erow << 8);
      int jc0 = jcp << 1, jc1 = jc0 | 1;
      float cs0 = 0.f, cs1 = 0.f;
      #pragma unroll
      for (int p = 0; p < 5; ++p) {
        float iv0 = gr[((p * 3 + 0) << 4) + jc0], iv1 = gr[((p * 3 + 0) << 4) + jc1];
        float fv0 = gr[((p * 3 + 1) << 4) + jc0], fv1 = gr[((p * 3 + 1) << 4) + jc1];
        float gv0 = gr[((p * 3 + 2) << 4) + jc0], gv1 = gr[((p * 3 + 2) << 4) + jc1];
        cr0[p] = sigf(fv0) * cr0[p] + sigf(iv0) * tanh_f(gv0);
        cr1[p] = sigf(fv1) * cr1[p] + sigf(iv1) * tanh_f(gv1);
        cs0 += cr0[p]; cs1 += cr1[p];
      }
      float h0 = sigf(gr[240 + jc0]) * tanh_f(cs0);
      float h1 = sigf(gr[240 + jc1]) * tanh_f(cs1);
      u32 val = (u32)f2bf(h0) | ((u32)f2bf(h1) << 16);
      u32* hw = (u32*)(hall + (size_t)(t + 1) * 65536) + (((bh << 6) | erow) << 8) + (jt << 3) + jcp;
      __hip_atomic_store(hw, val, __ATOMIC_RELAXED, __HIP_MEMORY_SCOPE_AGENT);
    }
    gbar(bar, t);
  }

  // ---- classifier + log_softmax: 2 batch rows per block (fp32 out) ----
  const u16* hT = hall + (size_t)T_SEQ * 65536;
  for (int r = 0; r < 2; ++r) {
    int row = (blockIdx.x << 1) + r;
    float lg = 0.f;
    if (tid < 60) {
      lg = fcb[tid];
      const u16* hr = hT + row * 512;
      for (int k = 0; k < 512; ++k)
        lg += bf2f(hr[k]) * fcw[k * 60 + tid];
      gsh[tid] = lg;
    }
    __syncthreads();
    if (tid == 0) {
      float mx = -1e30f;
      for (int c2 = 0; c2 < 60; ++c2) mx = fmaxf(mx, gsh[c2]);
      float s = 0.f;
      for (int c2 = 0; c2 < 60; ++c2) s += __expf(gsh[c2] - mx);
      gsh[63] = mx + __logf(s);
    }
    __syncthreads();
    if (tid < 60) out[row * 60 + tid] = lg - gsh[63];
    __syncthreads();
  }
}

extern "C" void kernel_launch(void* const* d_in, const int* in_sizes, int n_in,
                              void* d_out, int out_size, void* d_ws, size_t ws_size,
                              hipStream_t stream)
{
  const float* xin = (const float*)d_in[0];   // [5][128][300][30]
  const float* Wx  = (const float*)d_in[1];   // [5][30][1536]
  const float* Wh  = (const float*)d_in[2];   // [5][512][1536]
  const float* bg  = (const float*)d_in[3];   // [5][1536]
  const float* Wxo = (const float*)d_in[4];   // [150][512]
  const float* Who = (const float*)d_in[5];   // [512][512]
  const float* bo  = (const float*)d_in[6];   // [512]
  const float* fcw = (const float*)d_in[7];   // [512][60]
  const float* fcb = (const float*)d_in[8];   // [60]
  float* out = (float*)d_out;                 // [128][60]

  char* ws = (char*)d_ws;
  u16*   Wp    = (u16*)(ws + OFF_WP);
  float* bpack = (float*)(ws + OFF_BP);
  u16*   xb    = (u16*)(ws + OFF_XB);
  u16*   hall  = (u16*)(ws + OFF_H);
  int*   bar   = (int*)(ws + OFF_BAR);

  hipLaunchKernelGGL(prep, dim3(2688), dim3(256), 0, stream,
                     Wx, Wh, bg, Wxo, Who, bo, Wp, bpack, hall, bar);
  hipLaunchKernelGGL(prep_x, dim3(3600), dim3(256), 0, stream, xin, xb);

  void* args[] = { (void*)&xb, (void*)&Wp, (void*)&bpack, (void*)&hall,
                   (void*)&bar, (void*)&fcw, (void*)&fcb, (void*)&out };
  hipLaunchCooperativeKernel((void*)plstm, dim3(NBLK), dim3(NTHR), args, 0, stream);
}

// Round 3
// 2409.098 us; speedup vs baseline: 1.2211x; 1.2211x over previous
//
#include <hip/hip_runtime.h>

typedef unsigned short u16;
typedef unsigned int   u32;
typedef __attribute__((ext_vector_type(8))) short bf16x8;
typedef __attribute__((ext_vector_type(2))) float f32x2;
typedef __attribute__((ext_vector_type(4))) float f32x4;
typedef __attribute__((ext_vector_type(4))) u32 u32x4;

#define NBLK 64
#define NTHR 512
#define T_SEQ 300

// workspace layout (bytes) — all offsets 16B-aligned
#define OFF_WP   0u            // packed weights bf16: 512 tiles * 21 ksteps * 64 lanes * 16B = 11,010,048
#define OFF_BP   11010048u     // packed bias f32[8192] = 32,768
#define OFF_XB   11042816u     // x bf16 K-slot layout: 300*128*192*2 = 14,745,600
#define OFF_H    25788416u     // h arena bf16: 301 * 128*512 * 2B = 39,452,672
#define OFF_BAR  65241088u     // flags[64] (per-block publish counters)

__device__ __forceinline__ float bf2f(u16 u){ union { u32 u; float f; } v; v.u = ((u32)u) << 16; return v.f; }
__device__ __forceinline__ u16 f2bf(float f){
  union { float f; u32 u; } v; v.f = f;
  u32 r = v.u + 0x7fffu + ((v.u >> 16) & 1u);
  return (u16)(r >> 16);
}
__device__ __forceinline__ float sigf(float x){ return 1.f / (1.f + __expf(-x)); }
__device__ __forceinline__ float tanh_f(float x){ return 1.f - 2.f / (1.f + __expf(2.f * x)); }

// ---------------------------------------------------------------------------
// prep: pack fp32 weights into bf16 MFMA B-fragment order, pack biases (f32),
// zero h[0], reset flags. K-space per output column (672 = 21*32): [0,512) =
// hidden; [512,672) = 5 parts * 32 slots. Slot (p, cc, ii): d = cc*8+ii for
// cc<3; for cc==3, ii<2 -> weight ZERO (data duplicates x[22],x[23]),
// ii>=2 -> d = 22+ii. Gate tiles tt=p*3+g use part p's slots; o-tile (tt=15)
// uses all parts (Wxo).
// ---------------------------------------------------------------------------
__global__ void prep(const float* __restrict__ Wx, const float* __restrict__ Wh,
                     const float* __restrict__ bg, const float* __restrict__ Wxo,
                     const float* __restrict__ Who, const float* __restrict__ bo,
                     u16* __restrict__ Wp, float* __restrict__ bpack,
                     u16* __restrict__ h0, int* __restrict__ flags)
{
  int w = blockIdx.x * 256 + threadIdx.x;

  if (w < 8192) {
    u32x4 z = {0u, 0u, 0u, 0u};
    ((u32x4*)h0)[w] = z;                       // zero h[0] (128*512 bf16)
    int tile = w >> 4, jc = w & 15;
    int jt = tile >> 4, tt = tile & 15, j = (jt << 4) + jc;
    float bv;
    if (tt < 15) { int p = tt / 3, g = tt - p * 3; bv = bg[p * 1536 + g * 512 + j]; }
    else bv = bo[j];
    bpack[w] = bv;
  }
  if (w < 64) flags[w] = 0;

  int lane = w & 63, rem = w >> 6, kk = rem % 21, tile = rem / 21;
  if (tile < 512) {
    int jt = tile >> 4, tt = tile & 15;
    int j = (jt << 4) + (lane & 15);
    int k0 = kk * 32 + ((lane >> 4) << 3);
    union { u16 s[8]; u32x4 v; } o;
    #pragma unroll
    for (int i = 0; i < 8; ++i) {
      int k = k0 + i;
      float val = 0.f;
      if (tt < 15) {
        int p = tt / 3, g = tt - p * 3, col = g * 512 + j;
        if (k < 512) val = Wh[(p * 512 + k) * 1536 + col];
        else {
          int kx = k - 512, px = kx >> 5, cc = (kx >> 3) & 3, ii = kx & 7;
          int d = (cc < 3) ? cc * 8 + ii : ((ii < 2) ? -1 : 22 + ii);
          if (px == p && d >= 0) val = Wx[(p * 30 + d) * 1536 + col];
        }
      } else {
        if (k < 512) val = Who[k * 512 + j];
        else {
          int kx = k - 512, px = kx >> 5, cc = (kx >> 3) & 3, ii = kx & 7;
          int d = (cc < 3) ? cc * 8 + ii : ((ii < 2) ? -1 : 22 + ii);
          if (d >= 0) val = Wxo[(px * 30 + d) * 512 + j];
        }
      }
      o.s[i] = f2bf(val);
    }
    *(u32x4*)(Wp + (size_t)((tile * 21 + kk) * 64 + lane) * 8) = o.v;
  }
}

// ---------------------------------------------------------------------------
// prep_x: fp32 x [5][128][300][30] -> bf16 xb[t][bglob][slot] (slot 0..191,
// slots 160..191 zero pad). One thread = one 8-slot chunk (16B store).
// ---------------------------------------------------------------------------
__global__ void prep_x(const float* __restrict__ x, u16* __restrict__ xb)
{
  int w = blockIdx.x * 256 + threadIdx.x;          // 0 .. 921599
  int cx = w % 24, rem = w / 24;
  int bglob = rem % 128, t = rem / 128;
  union { u16 s[8]; u32x4 v; } o;
  int s0 = cx << 3;
  if (s0 >= 160) {
    u32x4 z = {0u, 0u, 0u, 0u}; o.v = z;
  } else {
    int p = s0 >> 5, cc = (s0 >> 3) & 3;
    const float* row = x + ((size_t)(p * 128 + bglob) * 300 + t) * 30;
    #pragma unroll
    for (int i = 0; i < 8; ++i) {
      int d = (cc < 3) ? cc * 8 + i : 22 + i;
      o.s[i] = f2bf(row[d]);
    }
  }
  *(u32x4*)(xb + (size_t)w * 8) = o.v;
}

// Distributed readiness wait: lane i polls flags[i] (relaxed agent loads,
// served at the coherence point). Every wave polls independently — no
// serialized RMW chain, no central generation store on the critical path.
__device__ __forceinline__ void wait_flags(const int* flags, int t)
{
  int lane = threadIdx.x & 63;
  for (;;) {
    int v = __hip_atomic_load(&flags[lane], __ATOMIC_RELAXED, __HIP_MEMORY_SCOPE_AGENT);
    if (__all(v >= t)) break;
  }
}

// ---------------------------------------------------------------------------
// Persistent part-LSTM. Block = (jt = 16-col slice of H) x (bh = batch half).
// Per step t: stage x (no h dependency) -> x-part MFMA (absorbs inter-block
// jitter) -> wait for all flags >= t -> stage h -> h-part MFMA -> gates to
// LDS [tile][row][16] -> elementwise c/h update (c in fp32 registers) ->
// publish h(t+1) (agent stores, vmcnt drained by __syncthreads) -> flag=t+1.
// ---------------------------------------------------------------------------
__global__ void __launch_bounds__(NTHR)
plstm(const u16* __restrict__ xb, const u16* __restrict__ Wp,
      const float* __restrict__ bpack, u16* hall, int* flags,
      const float* __restrict__ fcw, const float* __restrict__ fcb,
      float* __restrict__ out)
{
  __shared__ __align__(16) u16 Ash[64 * 512];     // 64 KB: h A-tiles (swizzled)
  __shared__ __align__(16) u16 Xsh[64 * 192];     // 24 KB: x K-slots (swizzled)
  __shared__ __align__(16) float gsh[16 * 64 * 16]; // 64 KB: gates [tt][row][16]

  const int tid  = threadIdx.x;
  const int lane = tid & 63;
  const int wv   = tid >> 6;          // 8 waves
  const int l15  = lane & 15;
  const int quad = lane >> 4;
  const int jt   = blockIdx.x >> 1;   // 0..31
  const int bh   = blockIdx.x & 1;    // batch half
  const int tt0  = wv << 1;           // this wave's two N-tiles

  const int erow = tid >> 3;          // elementwise: row 0..63
  const int jcp  = tid & 7;           // jc pair index

  float cr0[5], cr1[5];
  #pragma unroll
  for (int p = 0; p < 5; ++p) { cr0[p] = 0.f; cr1[p] = 0.f; }

  const u16* wpb0 = Wp + (size_t)((jt * 16 + tt0    ) * 21) * 512 + lane * 8;
  const u16* wpb1 = Wp + (size_t)((jt * 16 + tt0 + 1) * 21) * 512 + lane * 8;
  const float bias0 = bpack[((jt << 4) + tt0    ) * 16 + l15];
  const float bias1 = bpack[((jt << 4) + tt0 + 1) * 16 + l15];

  for (int t = 0; t < T_SEQ; ++t) {
    // ---- stage x[t] (own batch half) into LDS, chunk-XOR swizzle ----
    {
      const u16* xsrc = xb + (size_t)(t * 128 + (bh << 6)) * 192;
      #pragma unroll
      for (int i = 0; i < 3; ++i) {
        int c = tid + (i << 9);           // 0..1535
        int row = c / 24, cx = c - row * 24;
        u32x4 v = *(const u32x4*)(xsrc + (size_t)row * 192 + (cx << 3));
        *(u32x4*)(Xsh + row * 192 + ((cx ^ (row & 7)) << 3)) = v;
      }
    }
    __syncthreads();                      // Xsh ready (also: all waves past t-1)

    f32x4 acc0[4], acc1[4];
    #pragma unroll
    for (int m = 0; m < 4; ++m) {
      f32x4 z = {0.f, 0.f, 0.f, 0.f};
      acc0[m] = z; acc1[m] = z;
    }

    // ---- K-loop, x part (no h dependency — runs while others catch up) ----
    #pragma unroll
    for (int kk = 0; kk < 5; ++kk) {
      bf16x8 b0 = *(const bf16x8*)(wpb0 + (16 + kk) * 512);
      bf16x8 b1 = *(const bf16x8*)(wpb1 + (16 + kk) * 512);
      int cf = (kk << 2) | quad;
      #pragma unroll
      for (int m = 0; m < 4; ++m) {
        int row = (m << 4) | l15;
        bf16x8 a = *(const bf16x8*)(Xsh + row * 192 + ((cf ^ (row & 7)) << 3));
        acc0[m] = __builtin_amdgcn_mfma_f32_16x16x32_bf16(a, b0, acc0[m], 0, 0, 0);
        acc1[m] = __builtin_amdgcn_mfma_f32_16x16x32_bf16(a, b1, acc1[m], 0, 0, 0);
      }
    }

    // ---- wait until h(t) published by all blocks ----
    wait_flags(flags, t);

    // ---- stage h[t] rows (own batch half) into LDS, chunk-XOR swizzle ----
    const u16* hprev = hall + (size_t)t * 65536;
    #pragma unroll
    for (int i = 0; i < 8; ++i) {
      int c = tid + (i << 9);
      int row = c >> 6, cc = c & 63;
      u32x4 v = *(const u32x4*)(hprev + (size_t)(((bh << 6) | row) << 9) + (cc << 3));
      *(u32x4*)(Ash + (row << 9) + ((cc ^ (row & 7)) << 3)) = v;
    }
    __syncthreads();                      // Ash ready

    // ---- K-loop, hidden part (LDS A-frags) ----
    #pragma unroll 4
    for (int kk = 0; kk < 16; ++kk) {
      bf16x8 b0 = *(const bf16x8*)(wpb0 + kk * 512);
      bf16x8 b1 = *(const bf16x8*)(wpb1 + kk * 512);
      int c0 = (kk << 2) | quad;
      #pragma unroll
      for (int m = 0; m < 4; ++m) {
        int row = (m << 4) | l15;
        bf16x8 a = *(const bf16x8*)(Ash + (row << 9) + ((c0 ^ (row & 7)) << 3));
        acc0[m] = __builtin_amdgcn_mfma_f32_16x16x32_bf16(a, b0, acc0[m], 0, 0, 0);
        acc1[m] = __builtin_amdgcn_mfma_f32_16x16x32_bf16(a, b1, acc1[m], 0, 0, 0);
      }
    }

    // ---- gates (+bias) to gsh [tt][row][16] (no sync needed: gsh disjoint) ----
    #pragma unroll
    for (int m = 0; m < 4; ++m) {
      #pragma unroll
      for (int r = 0; r < 4; ++r) {
        int row = (m << 4) + (quad << 2) + r;
        gsh[ tt0      * 1024 + row * 16 + l15] = acc0[m][r] + bias0;
        gsh[(tt0 + 1) * 1024 + row * 16 + l15] = acc1[m][r] + bias1;
      }
    }
    __syncthreads();                      // gates ready

    // ---- elementwise: c update (registers), h(t+1) -> agent-scope store ----
    {
      const float* gbase = gsh + erow * 16 + (jcp << 1);
      float cs0 = 0.f, cs1 = 0.f;
      #pragma unroll
      for (int p = 0; p < 5; ++p) {
        f32x2 iv = *(const f32x2*)(gbase + (p * 3 + 0) * 1024);
        f32x2 fv = *(const f32x2*)(gbase + (p * 3 + 1) * 1024);
        f32x2 gv = *(const f32x2*)(gbase + (p * 3 + 2) * 1024);
        cr0[p] = sigf(fv.x) * cr0[p] + sigf(iv.x) * tanh_f(gv.x);
        cr1[p] = sigf(fv.y) * cr1[p] + sigf(iv.y) * tanh_f(gv.y);
        cs0 += cr0[p]; cs1 += cr1[p];
      }
      f32x2 ov = *(const f32x2*)(gbase + 15 * 1024);
      float h0 = sigf(ov.x) * tanh_f(cs0);
      float h1 = sigf(ov.y) * tanh_f(cs1);
      u32 val = (u32)f2bf(h0) | ((u32)f2bf(h1) << 16);
      u32* hw = (u32*)(hall + (size_t)(t + 1) * 65536) + (((bh << 6) | erow) << 8) + (jt << 3) + jcp;
      __hip_atomic_store(hw, val, __ATOMIC_RELAXED, __HIP_MEMORY_SCOPE_AGENT);
    }
    __syncthreads();                      // drains vmcnt -> h(t+1) visible
    if (tid == 0)
      __hip_atomic_store(&flags[blockIdx.x], t + 1, __ATOMIC_RELAXED, __HIP_MEMORY_SCOPE_AGENT);
  }

  // ---- classifier + log_softmax: 2 batch rows per block, K-sliced ----
  wait_flags(flags, T_SEQ);
  __syncthreads();
  const u16* hT = hall + (size_t)T_SEQ * 65536;
  for (int r = 0; r < 2; ++r) {
    int row = (blockIdx.x << 1) + r;
    int c = tid & 63, ks = tid >> 6;      // 8 K-slices of 64
    float s = 0.f;
    if (c < 60) {
      const u16* hr = hT + row * 512 + ks * 64;
      const float* wr = fcw + (size_t)(ks * 64) * 60 + c;
      #pragma unroll 8
      for (int k = 0; k < 64; ++k) s += bf2f(hr[k]) * wr[k * 60];
    }
    gsh[ks * 64 + c] = s;
    __syncthreads();
    if (tid < 60) {
      float lg = fcb[tid];
      #pragma unroll
      for (int i = 0; i < 8; ++i) lg += gsh[i * 64 + tid];
      gsh[512 + tid] = lg;
    }
    __syncthreads();
    if (tid == 0) {
      float mx = -1e30f;
      for (int c2 = 0; c2 < 60; ++c2) mx = fmaxf(mx, gsh[512 + c2]);
      float sm = 0.f;
      for (int c2 = 0; c2 < 60; ++c2) sm += __expf(gsh[512 + c2] - mx);
      gsh[600] = mx + __logf(sm);
    }
    __syncthreads();
    if (tid < 60) out[row * 60 + tid] = gsh[512 + tid] - gsh[600];
    __syncthreads();
  }
}

extern "C" void kernel_launch(void* const* d_in, const int* in_sizes, int n_in,
                              void* d_out, int out_size, void* d_ws, size_t ws_size,
                              hipStream_t stream)
{
  const float* xin = (const float*)d_in[0];   // [5][128][300][30]
  const float* Wx  = (const float*)d_in[1];   // [5][30][1536]
  const float* Wh  = (const float*)d_in[2];   // [5][512][1536]
  const float* bg  = (const float*)d_in[3];   // [5][1536]
  const float* Wxo = (const float*)d_in[4];   // [150][512]
  const float* Who = (const float*)d_in[5];   // [512][512]
  const float* bo  = (const float*)d_in[6];   // [512]
  const float* fcw = (const float*)d_in[7];   // [512][60]
  const float* fcb = (const float*)d_in[8];   // [60]
  float* out = (float*)d_out;                 // [128][60]

  char* ws = (char*)d_ws;
  u16*   Wp    = (u16*)(ws + OFF_WP);
  float* bpack = (float*)(ws + OFF_BP);
  u16*   xb    = (u16*)(ws + OFF_XB);
  u16*   hall  = (u16*)(ws + OFF_H);
  int*   flags = (int*)(ws + OFF_BAR);

  hipLaunchKernelGGL(prep, dim3(2688), dim3(256), 0, stream,
                     Wx, Wh, bg, Wxo, Who, bo, Wp, bpack, hall, flags);
  hipLaunchKernelGGL(prep_x, dim3(3600), dim3(256), 0, stream, xin, xb);

  void* args[] = { (void*)&xb, (void*)&Wp, (void*)&bpack, (void*)&hall,
                   (void*)&flags, (void*)&fcw, (void*)&fcb, (void*)&out };
  hipLaunchCooperativeKernel((void*)plstm, dim3(NBLK), dim3(NTHR), args, 0, stream);
}

// Round 5
// 1932.397 us; speedup vs baseline: 1.5223x; 1.2467x over previous
//
#include <hip/hip_runtime.h>

typedef unsigned short u16;
typedef unsigned int   u32;
typedef unsigned long long u64;
typedef __attribute__((ext_vector_type(8))) short bf16x8;
typedef __attribute__((ext_vector_type(16))) float f32x16;
typedef __attribute__((ext_vector_type(4))) float f32x4;
typedef __attribute__((ext_vector_type(4))) u32 u32x4;

#define T_SEQ 300

// workspace layout (bytes) — all offsets 16B-aligned
#define OFF_WP   0u            // packed A-frag weights bf16: 256 jp * 42 kk * 64 lanes * 16B = 11,010,048
#define OFF_BP   11010048u     // packed bias f32 [512 j][16 g] = 32,768
#define OFF_XB   11042816u     // x bf16 K-slot layout: 300*128*192*2 = 14,745,600
#define OFF_H    25788416u     // h arena bf16: 301 * 128*512 * 2B = 39,452,672
#define OFF_FL   65241088u     // flags[128] = [bq 4][32 jgh]

__device__ __forceinline__ float bf2f(u16 u){ union { u32 u; float f; } v; v.u = ((u32)u) << 16; return v.f; }
__device__ __forceinline__ u16 f2bf(float f){
  union { float f; u32 u; } v; v.f = f;
  u32 r = v.u + 0x7fffu + ((v.u >> 16) & 1u);
  return (u16)(r >> 16);
}
__device__ __forceinline__ float sigf(float x){ return 1.f / (1.f + __expf(-x)); }
__device__ __forceinline__ float tanh_f(float x){ return 1.f - 2.f / (1.f + __expf(2.f * x)); }

// ---------------------------------------------------------------------------
// prep: pack fp32 weights into 32x32x16 MFMA *A-operand* fragments (weights on
// the M side; gates in M). M-row m -> (jj=(m>>2)&1, g=(m&3)+4*(m>>3)); with the
// C/D layout row=(reg&3)+8*(reg>>2)+4*(lane>>5) this makes acc[reg]=gate reg
// for j=jp*2+(lane>>5) per lane. A[m][k]: m=lane&31, k=kk*16+(lane>>5)*8+i
// (same per-lane k-convention used for the B pack — a uniform k-permutation
// cancels between operands). K-space (672): [0,512)=hidden, [512,672)=
// 5 parts * 32 slots (slot (p,cc,ii): d=cc*8+ii for cc<3; cc==3: ii<2 -> ZERO
// weight (data dups x[22],x[23]), ii>=2 -> d=22+ii). g<15: part p=g/3, type
// g%3 (own part only); g==15: shared o-gate (Who/Wxo, all parts).
// Also: bias pack [j][16], zero h[0], reset flags.
// ---------------------------------------------------------------------------
__global__ void prep(const float* __restrict__ Wx, const float* __restrict__ Wh,
                     const float* __restrict__ bg, const float* __restrict__ Wxo,
                     const float* __restrict__ Who, const float* __restrict__ bo,
                     u16* __restrict__ Wp, float* __restrict__ bpack,
                     u16* __restrict__ h0, int* __restrict__ flags)
{
  int w = blockIdx.x * 256 + threadIdx.x;     // 0 .. 688127 = 256 jp * 42 kk * 64 lanes

  if (w < 8192) {
    u32x4 z = {0u, 0u, 0u, 0u};
    ((u32x4*)h0)[w] = z;                      // zero h[0] (128*512 bf16)
    int j = w >> 4, g = w & 15;
    float bv;
    if (g < 15) { int p = g / 3, t3 = g - p * 3; bv = bg[p * 1536 + t3 * 512 + j]; }
    else bv = bo[j];
    bpack[w] = bv;
  }
  if (w < 128) flags[w] = 0;

  int lane = w & 63, rem = w >> 6;
  int kk = rem % 42, jp = rem / 42;           // jp 0..255
  int m = lane & 31, hi = lane >> 5;
  int jj = (m >> 2) & 1, g = (m & 3) + 4 * (m >> 3);
  int j = jp * 2 + jj;
  union { u16 s[8]; u32x4 v; } o;
  #pragma unroll
  for (int i = 0; i < 8; ++i) {
    int k = kk * 16 + hi * 8 + i;
    float val = 0.f;
    if (g < 15) {
      int p = g / 3, t3 = g - p * 3, col = t3 * 512 + j;
      if (k < 512) val = Wh[(p * 512 + k) * 1536 + col];
      else {
        int s = k - 512, px = s >> 5, cc = (s >> 3) & 3, ii = s & 7;
        int d = (cc < 3) ? cc * 8 + ii : ((ii < 2) ? -1 : 22 + ii);
        if (px == p && d >= 0) val = Wx[(p * 30 + d) * 1536 + col];
      }
    } else {
      if (k < 512) val = Who[k * 512 + j];
      else {
        int s = k - 512, px = s >> 5, cc = (s >> 3) & 3, ii = s & 7;
        int d = (cc < 3) ? cc * 8 + ii : ((ii < 2) ? -1 : 22 + ii);
        if (d >= 0) val = Wxo[(px * 30 + d) * 512 + j];
      }
    }
    o.s[i] = f2bf(val);
  }
  *(u32x4*)(Wp + ((size_t)(jp * 42 + kk) * 64 + lane) * 8) = o.v;
}

// ---------------------------------------------------------------------------
// prep_x: fp32 x [5][128][300][30] -> bf16 xb[t][bglob][slot] (slot 0..191,
// slots 160..191 zero pad). One thread = one 8-slot chunk (16B store).
// ---------------------------------------------------------------------------
__global__ void prep_x(const float* __restrict__ x, u16* __restrict__ xb)
{
  int w = blockIdx.x * 256 + threadIdx.x;     // 0 .. 921599
  int cx = w % 24, rem = w / 24;
  int bglob = rem % 128, t = rem / 128;
  union { u16 s[8]; u32x4 v; } o;
  int s0 = cx << 3;
  if (s0 >= 160) {
    u32x4 z = {0u, 0u, 0u, 0u}; o.v = z;
  } else {
    int p = s0 >> 5, cc = (s0 >> 3) & 3;
    const float* row = x + ((size_t)(p * 128 + bglob) * 300 + t) * 30;
    #pragma unroll
    for (int i = 0; i < 8; ++i) {
      int d = (cc < 3) ? cc * 8 + i : 22 + i;
      o.s[i] = f2bf(row[d]);
    }
  }
  *(u32x4*)(xb + (size_t)w * 8) = o.v;
}

// Distributed readiness: two lanes poll each of the 32 flags of one batch
// quarter (relaxed agent loads). No serialized RMW chain.
__device__ __forceinline__ void wait_flags32(const int* f, int t)
{
  int l = threadIdx.x & 31;
  for (;;) {
    int v = __hip_atomic_load(&f[l], __ATOMIC_RELAXED, __HIP_MEMORY_SCOPE_AGENT);
    if (__all(v >= t)) break;
  }
}

// ---------------------------------------------------------------------------
// Persistent part-LSTM, gate-in-lane formulation.
// 128 blocks x 512 threads (8 waves, 2/SIMD; co-residency margin 2x).
// Block = (bq: batch quarter, 32 rows) x (jgh: 16 hidden cols). Wave = one
// 32x32x16-MFMA tile chain: M=32 (16 gates x 2 j), N=32 batch rows, K=672,
// jp = jgh*8 + wave. Weights resident in 168 VGPRs (loaded once). Per step:
// stage x -> x-K MFMAs (no h dep, absorbs jitter) -> wait own-bq flags ->
// stage h -> 32 h-K MFMAs -> per-lane c/h update (acc[g] = gate g for
// (j=jp*2+hi, b=bq*32+(lane&31))) -> publish via LDS transpose -> flag.
// ---------------------------------------------------------------------------
__global__ void __launch_bounds__(512, 2)
plstm(const u16* __restrict__ xb, const u16* __restrict__ Wp,
      const float* __restrict__ bpack, u16* hall, int* flags,
      const float* __restrict__ fcw, const float* __restrict__ fcb,
      float* __restrict__ out)
{
  __shared__ __align__(16) u16 Hsh[32 * 512];   // 32 KB: h rows [b][64 chunks] (xor-swizzled)
  __shared__ __align__(16) u16 Xsh[32 * 256];   // 16 KB: x rows [b][32 chunks] (xor-swizzled)
  __shared__ __align__(16) u16 hbuf[32 * 16];   // 1 KB: h publish staging

  const int tid  = threadIdx.x;
  const int lane = tid & 63;
  const int wv   = tid >> 6;          // 8 waves
  const int n    = lane & 31;         // batch row within quarter
  const int hi   = lane >> 5;         // k-half / j-parity
  const int bq   = blockIdx.x >> 5;   // 0..3
  const int jgh  = blockIdx.x & 31;   // 0..31 (16 j each)
  const int jp   = jgh * 8 + wv;      // j-pair 0..255
  const int j    = jp * 2 + hi;       // this lane's hidden col
  int* myflags = flags + bq * 32;

  // resident A-fragments (weights), 42 ksteps x 4 VGPRs = 168 VGPRs
  bf16x8 afr[42];
  {
    const u16* wpb = Wp + ((size_t)jp * 42 * 64 + lane) * 8;
    #pragma unroll
    for (int kk = 0; kk < 42; ++kk)
      afr[kk] = *(const bf16x8*)(wpb + kk * 512);
  }
  float bias[16];
  #pragma unroll
  for (int i = 0; i < 4; ++i)
    *(f32x4*)(bias + i * 4) = *(const f32x4*)(bpack + j * 16 + i * 4);

  float cst[5] = {0.f, 0.f, 0.f, 0.f, 0.f};

  for (int t = 0; t < T_SEQ; ++t) {
    // ---- stage x[t] rows (own quarter) into LDS, chunk-XOR swizzle ----
    {
      const u16* xsrc = xb + (size_t)(t * 128 + bq * 32) * 192;
      #pragma unroll
      for (int i = 0; i < 2; ++i) {
        int c = tid + (i << 9);           // 0..1023, valid < 768 = 32 rows * 24 chunks
        if (c < 768) {
          int b = c / 24, cx = c - b * 24;
          u32x4 v = *(const u32x4*)(xsrc + b * 192 + (cx << 3));
          *(u32x4*)(Xsh + (b << 8) + (((cx ^ b) & 31) << 3)) = v;
        }
      }
    }
    __syncthreads();

    f32x16 acc;
    #pragma unroll
    for (int i = 0; i < 16; ++i) acc[i] = 0.f;

    // ---- K-loop, x part (no h dependency — absorbs inter-block jitter) ----
    #pragma unroll
    for (int kx = 0; kx < 10; ++kx) {
      int c = kx * 2 + hi;                // chunk 0..19
      bf16x8 bf = *(const bf16x8*)(Xsh + (n << 8) + (((c ^ n) & 31) << 3));
      acc = __builtin_amdgcn_mfma_f32_32x32x16_bf16(afr[32 + kx], bf, acc, 0, 0, 0);
    }

    // ---- wait until h(t) published by all 32 blocks of my batch quarter ----
    wait_flags32(myflags, t);

    // ---- stage h[t] rows (own quarter) into LDS, chunk-XOR swizzle ----
    {
      const u16* hsrc = hall + (size_t)t * 65536 + ((bq * 32) << 9);
      #pragma unroll
      for (int i = 0; i < 4; ++i) {
        int c = tid + (i << 9);           // 0..2047 = 32 rows * 64 chunks
        int b = c >> 6, cx = c & 63;
        u32x4 v = *(const u32x4*)(hsrc + (b << 9) + (cx << 3));
        int phys = (cx & 32) | ((cx ^ b) & 31);
        *(u32x4*)(Hsh + (b << 9) + (phys << 3)) = v;
      }
    }
    __syncthreads();

    // ---- K-loop, hidden part ----
    #pragma unroll
    for (int kk = 0; kk < 32; ++kk) {
      int c = kk * 2 + hi;                // chunk 0..63
      int phys = (c & 32) | ((c ^ n) & 31);
      bf16x8 bf = *(const bf16x8*)(Hsh + (n << 9) + (phys << 3));
      acc = __builtin_amdgcn_mfma_f32_32x32x16_bf16(afr[kk], bf, acc, 0, 0, 0);
    }

    // ---- per-lane elementwise: acc[g] = gate g for (j, b) ----
    float cs = 0.f;
    #pragma unroll
    for (int p = 0; p < 5; ++p) {
      float iv = acc[p * 3 + 0] + bias[p * 3 + 0];
      float fv = acc[p * 3 + 1] + bias[p * 3 + 1];
      float gv = acc[p * 3 + 2] + bias[p * 3 + 2];
      cst[p] = sigf(fv) * cst[p] + sigf(iv) * tanh_f(gv);
      cs += cst[p];
    }
    float hv = sigf(acc[15] + bias[15]) * tanh_f(cs);

    // ---- publish h(t+1): LDS transpose -> 16B agent-scope stores ----
    hbuf[(n << 4) + (wv << 1) + hi] = f2bf(hv);
    __syncthreads();
    if (tid < 64) {
      int row = tid >> 1, half = tid & 1;
      const u16* src = hbuf + (row << 4) + (half << 3);
      u64 v0 = *(const u64*)(src);
      u64 v1 = *(const u64*)(src + 4);
      u64* dst = (u64*)(hall + (size_t)(t + 1) * 65536
                        + (size_t)(bq * 32 + row) * 512 + (jgh << 4) + (half << 3));
      __hip_atomic_store(dst,     v0, __ATOMIC_RELAXED, __HIP_MEMORY_SCOPE_AGENT);
      __hip_atomic_store(dst + 1, v1, __ATOMIC_RELAXED, __HIP_MEMORY_SCOPE_AGENT);
    }
    __syncthreads();                      // drains vmcnt -> h(t+1) visible
    if (tid == 0)
      __hip_atomic_store(&myflags[jgh], t + 1, __ATOMIC_RELAXED, __HIP_MEMORY_SCOPE_AGENT);
  }

  // ---- classifier + log_softmax: blocks 0..63 do 2 batch rows each ----
  if (blockIdx.x >= 64) return;
  for (;;) {
    int v0 = __hip_atomic_load(&flags[lane],      __ATOMIC_RELAXED, __HIP_MEMORY_SCOPE_AGENT);
    int v1 = __hip_atomic_load(&flags[64 + lane], __ATOMIC_RELAXED, __HIP_MEMORY_SCOPE_AGENT);
    if (__all(min(v0, v1) >= T_SEQ)) break;
  }
  __syncthreads();
  float* fsh = (float*)Hsh;
  const u16* hT = hall + (size_t)T_SEQ * 65536;
  for (int r = 0; r < 2; ++r) {
    int row = blockIdx.x * 2 + r;
    int ks = tid >> 6, c = tid & 63;      // 8 K-slices of 64
    float s = 0.f;
    if (c < 60) {
      const u16* hr = hT + row * 512 + ks * 64;
      const float* wr = fcw + (size_t)(ks * 64) * 60 + c;
      #pragma unroll 8
      for (int k = 0; k < 64; ++k) s += bf2f(hr[k]) * wr[k * 60];
    }
    __syncthreads();
    fsh[ks * 64 + c] = s;
    __syncthreads();
    if (tid < 60) {
      float lg = fcb[tid];
      #pragma unroll
      for (int i = 0; i < 8; ++i) lg += fsh[i * 64 + tid];
      fsh[512 + tid] = lg;
    }
    __syncthreads();
    if (tid == 0) {
      float mx = -1e30f;
      for (int i = 0; i < 60; ++i) mx = fmaxf(mx, fsh[512 + i]);
      float sm = 0.f;
      for (int i = 0; i < 60; ++i) sm += __expf(fsh[512 + i] - mx);
      fsh[576] = mx + __logf(sm);
    }
    __syncthreads();
    if (tid < 60) out[row * 60 + tid] = fsh[512 + tid] - fsh[576];
    __syncthreads();
  }
}

extern "C" void kernel_launch(void* const* d_in, const int* in_sizes, int n_in,
                              void* d_out, int out_size, void* d_ws, size_t ws_size,
                              hipStream_t stream)
{
  const float* xin = (const float*)d_in[0];   // [5][128][300][30]
  const float* Wx  = (const float*)d_in[1];   // [5][30][1536]
  const float* Wh  = (const float*)d_in[2];   // [5][512][1536]
  const float* bg  = (const float*)d_in[3];   // [5][1536]
  const float* Wxo = (const float*)d_in[4];   // [150][512]
  const float* Who = (const float*)d_in[5];   // [512][512]
  const float* bo  = (const float*)d_in[6];   // [512]
  const float* fcw = (const float*)d_in[7];   // [512][60]
  const float* fcb = (const float*)d_in[8];   // [60]
  float* out = (float*)d_out;                 // [128][60]

  char* ws = (char*)d_ws;
  u16*   Wp    = (u16*)(ws + OFF_WP);
  float* bpack = (float*)(ws + OFF_BP);
  u16*   xb    = (u16*)(ws + OFF_XB);
  u16*   hall  = (u16*)(ws + OFF_H);
  int*   flags = (int*)(ws + OFF_FL);

  hipLaunchKernelGGL(prep, dim3(2688), dim3(256), 0, stream,
                     Wx, Wh, bg, Wxo, Who, bo, Wp, bpack, hall, flags);
  hipLaunchKernelGGL(prep_x, dim3(3600), dim3(256), 0, stream, xin, xb);

  void* args[] = { (void*)&xb, (void*)&Wp, (void*)&bpack, (void*)&hall,
                   (void*)&flags, (void*)&fcw, (void*)&fcb, (void*)&out };
  hipLaunchCooperativeKernel((void*)plstm, dim3(128), dim3(512), args, 0, stream);
}